// Round 11
// baseline (290.926 us; speedup 1.0000x reference)
//
#include <hip/hip_runtime.h>

using uint = unsigned int;
using ushort = unsigned short;

typedef __attribute__((ext_vector_type(8))) short bf16x8;
typedef __attribute__((ext_vector_type(4))) short bf16x4;
typedef __attribute__((ext_vector_type(4))) float f32x4;

#define ADMM_ITERS 100
#define RHO_C 1.0f
#define SIGMA_C 1e-6f

__device__ inline ushort f2bf(float f) {
  union { float f; uint u; } c; c.f = f;
  uint u = c.u;
  uint r = (u + 0x7fffu + ((u >> 16) & 1u)) >> 16;
  return (ushort)r;
}

__device__ inline void gload_lds16(const void* g, void* l) {
  __builtin_amdgcn_global_load_lds(
      (const __attribute__((address_space(1))) void*)g,
      (__attribute__((address_space(3))) void*)l, 16, 0, 0);
}

// Split 8 f32 -> hi/lo bf16x8 by TRUNCATION (hi = mantissa-masked; lo = exact
// residual, truncated). Residual error ~2^-16 relative.
__device__ inline void splitPack(const float* x, bf16x8& hi, bf16x8& lo) {
#pragma unroll
  for (int j = 0; j < 8; ++j) {
    uint b = __float_as_uint(x[j]);
    uint hb = b & 0xffff0000u;
    float lf = x[j] - __uint_as_float(hb);
    hi[j] = (short)(b >> 16);
    lo[j] = (short)(__float_as_uint(lf) >> 16);
  }
}

// ---------------------------------------------------------------------------
// prep bodies (fused into prep_all)
// ---------------------------------------------------------------------------
__device__ void transpose_body(const float* __restrict__ in, ushort* __restrict__ out,
                               int R, int C, int Cout, int bx, int by, int tid) {
  __shared__ float t[32][33];
  const int c0 = bx * 32, r0 = by * 32;
  const int tx = tid & 31, ty = tid >> 5;
  for (int rr = ty; rr < 32; rr += 8) {
    int r = r0 + rr, c = c0 + tx;
    float v = 0.0f;
    if (r < R && c < C) v = in[(long)r * C + c];
    t[rr][tx] = v;
  }
  __syncthreads();
  for (int rr = ty; rr < 32; rr += 8) {
    int c = c0 + rr, r = r0 + tx;
    if (c < Cout && r < R) out[(long)c * R + r] = f2bf(t[tx][rr]);
  }
}

// ADMM setup -> MFMA operand form (round-0 layout, no permutation).
// W-state iteration (verified): u = 2*clip(W)-W,
//   W' = base + T*u + (W - Z),  T = [[2Minv, G],[2*A12*Minv, A12*G]] (36x36)
//   base = T0*q per row,       T0 = [[Minv],[A12*Minv]] (36x24)
// Outputs row-major [n_out][k_in], bf16 hi+lo (rounded split):
// Th/Tl [48][64], T0h/T0l [48][32], bounds bl/bu [48].
__device__ void setup_body(const float* __restrict__ Aeq, const float* __restrict__ beq,
                           const float* __restrict__ A, const float* __restrict__ b,
                           const float* __restrict__ ub, const float* __restrict__ lb,
                           ushort* __restrict__ Th, ushort* __restrict__ Tl,
                           ushort* __restrict__ T0h, ushort* __restrict__ T0l,
                           float* __restrict__ blp, float* __restrict__ bup, int t) {
  __shared__ float Aug[24][48];
  __shared__ float A12[12 * 24];
  __shared__ float fac[24];
  __shared__ float Tx[24][36];
  for (int i = t; i < 48 * 64; i += 256) { Th[i] = 0; Tl[i] = 0; }
  for (int i = t; i < 48 * 32; i += 256) { T0h[i] = 0; T0l[i] = 0; }
  if (t < 96)  A12[t] = Aeq[t];
  if (t < 192) A12[96 + t] = A[t];
  __syncthreads();
  for (int idx = t; idx < 576; idx += 256) {
    int j = idx / 24, k = idx % 24;
    float s = (j == k) ? (1.0f + SIGMA_C + 2.0f * RHO_C) : 0.0f;
    for (int r = 0; r < 12; ++r) s += RHO_C * A12[r * 24 + j] * A12[r * 24 + k];
    Aug[j][k] = s;
    Aug[j][24 + k] = (j == k) ? 1.0f : 0.0f;
  }
  __syncthreads();
  for (int p = 0; p < 24; ++p) {
    float rp = 1.0f / Aug[p][p];
    if (t < 24) fac[t] = Aug[t][p];
    __syncthreads();
    if (t < 48) Aug[p][t] *= rp;
    __syncthreads();
    for (int idx = t; idx < 24 * 48; idx += 256) {
      int r = idx / 48, c = idx % 48;
      if (r != p) Aug[r][c] -= fac[r] * Aug[p][c];
    }
    __syncthreads();
  }
  auto splitStore = [](ushort* hp, ushort* lp, int i, float v) {
    ushort hs = f2bf(v);
    float hf = __uint_as_float(((uint)hs) << 16);
    ushort ls = f2bf(v - hf);
    hp[i] = hs; lp[i] = ls;
  };
  for (int idx = t; idx < 24 * 36; idx += 256) {
    int n = idx / 36, k = idx % 36;
    float v;
    if (k < 24) v = 2.0f * Aug[n][24 + k];
    else {
      v = 0.0f;
      for (int j = 0; j < 24; ++j) v += Aug[n][24 + j] * A12[(k - 24) * 24 + j];
    }
    Tx[n][k] = v;
    splitStore(Th, Tl, n * 64 + k, v);
  }
  __syncthreads();
  for (int idx = t; idx < 12 * 36; idx += 256) {
    int m = idx / 36, k = idx % 36;
    float v = 0.0f;
    for (int j = 0; j < 24; ++j) v += A12[m * 24 + j] * Tx[j][k];
    splitStore(Th, Tl, (24 + m) * 64 + k, v);
  }
  for (int idx = t; idx < 36 * 24; idx += 256) {
    int n = idx / 24, k = idx % 24;
    float v;
    if (n < 24) v = Aug[n][24 + k];
    else {
      v = 0.0f;
      for (int j = 0; j < 24; ++j) v += A12[(n - 24) * 24 + j] * Aug[j][24 + k];
    }
    splitStore(T0h, T0l, n * 32 + k, v);
  }
  if (t < 48) {
    float lv, uv;
    if (t < 24)      { lv = lb[t]; uv = ub[t]; }
    else if (t < 28) { lv = beq[t - 24]; uv = lv; }
    else if (t < 36) { lv = -1e30f; uv = b[t - 28]; }
    else             { lv = -1e30f; uv = 1e30f; }
    blp[t] = lv; bup[t] = uv;
  }
}

// Fused prep: [0,nConv) convert | [+512) W1T | [+1024) W2T | [+32) W3T | [1) setup
__global__ void prep_all(
    const float* __restrict__ state, ushort* __restrict__ stateB, int n4,
    const float* __restrict__ W1, ushort* __restrict__ W1T,
    const float* __restrict__ W2, ushort* __restrict__ W2T,
    const float* __restrict__ W3, ushort* __restrict__ W3T,
    const float* __restrict__ Aeq, const float* __restrict__ beq,
    const float* __restrict__ A, const float* __restrict__ b,
    const float* __restrict__ ub, const float* __restrict__ lb,
    ushort* __restrict__ Th, ushort* __restrict__ Tl,
    ushort* __restrict__ T0h, ushort* __restrict__ T0l,
    float* __restrict__ blp, float* __restrict__ bup) {
  const int nConv = n4 >> 8;
  int bb = blockIdx.x;
  if (bb < nConv) {
    int i = bb * 256 + threadIdx.x;
    if (i < n4) {
      float4 v = ((const float4*)state)[i];
      uint2 p;
      p.x = (uint)f2bf(v.x) | ((uint)f2bf(v.y) << 16);
      p.y = (uint)f2bf(v.z) | ((uint)f2bf(v.w) << 16);
      ((uint2*)stateB)[i] = p;
    }
    return;
  }
  bb -= nConv;
  if (bb < 512)  { transpose_body(W1, W1T, 512, 1024, 1024, bb & 31, bb >> 5, threadIdx.x); return; }
  bb -= 512;
  if (bb < 1024) { transpose_body(W2, W2T, 1024, 1024, 1024, bb & 31, bb >> 5, threadIdx.x); return; }
  bb -= 1024;
  if (bb < 32)   { transpose_body(W3, W3T, 1024, 24, 32, 0, bb, threadIdx.x); return; }
  setup_body(Aeq, beq, A, b, ub, lb, Th, Tl, T0h, T0l, blp, bup, threadIdx.x);
}

// ---------------------------------------------------------------------------
// 256x256 8-phase bf16 GEMM (T1+T2+T3+T4+T5).
// Round-11: epilogue rewritten — was per-element scalar ushort stores (128 KB
// C-tile/WG at 2B granularity = the K-independent fixed cost that made
// K=512 and K=1024 run equally at ~53 µs). Now: per mi-slice (32 rows x 256
// cols bf16) bounce through LDS (row pad +8 ushorts -> <=2-way banks), then
// fully-coalesced 16B/lane global stores. Math unchanged (bias->relu->f2bf).
// ---------------------------------------------------------------------------
#define GEMM8P_QUAD(MI0, NJ0)                                                 \
  _Pragma("unroll") for (int mi_ = 0; mi_ < 4; ++mi_)                         \
  _Pragma("unroll") for (int nj_ = 0; nj_ < 2; ++nj_)                         \
  _Pragma("unroll") for (int kk_ = 0; kk_ < 2; ++kk_)                         \
    acc[(MI0) + mi_][(NJ0) + nj_] = __builtin_amdgcn_mfma_f32_16x16x32_bf16(  \
        aF[mi_][kk_], bF[(NJ0) + nj_][kk_], acc[(MI0) + mi_][(NJ0) + nj_],    \
        0, 0, 0);

#define GEMM8P_SYNC_PRE()                              \
  __builtin_amdgcn_s_barrier();                        \
  asm volatile("s_waitcnt lgkmcnt(0)" ::: "memory");   \
  __builtin_amdgcn_sched_barrier(0);                   \
  __builtin_amdgcn_s_setprio(1);

#define GEMM8P_SYNC_POST()                             \
  __builtin_amdgcn_s_setprio(0);                       \
  __builtin_amdgcn_s_barrier();

__global__ __launch_bounds__(512, 2) void gemm8p(
    const ushort* __restrict__ A, const ushort* __restrict__ Bt,
    const float* __restrict__ bias, ushort* __restrict__ Cout,
    int K, int ldc, int nblk_n) {
  __shared__ __align__(16) char ldsc[131072];   // [2 buf][A 32K | B 32K]

  const int nwg = gridDim.x;
  const int bid = blockIdx.x;
  const int swz = (bid & 7) * (nwg >> 3) + (bid >> 3);
  const int blockM = (swz / nblk_n) * 256;
  const int blockN = (swz % nblk_n) * 256;

  const int tid = threadIdx.x;
  const int wave = tid >> 6;
  const int lane = tid & 63;
  const int l15 = lane & 15;
  const int q = lane >> 4;
  const int wm = (wave >> 2) * 128;
  const int wn = (wave & 3) * 64;
  const int nt = K >> 6;

  f32x4 acc[8][4] = {};

  auto stage = [&](int ts, int h) {
    if (ts >= nt) return;
    char* base = ldsc + ((ts & 1) << 16) + (h << 14);
#pragma unroll
    for (int j = 0; j < 2; ++j) {
      const int idx = wave * 64 + j * 512 + lane;
      const int row = idx >> 3;
      const int cs = (idx & 7) ^ (row & 7);
      const ushort* gp =
          (h < 2 ? A + (long)(blockM + ((h & 1) << 7) + row) * K
                 : Bt + (long)(blockN + ((h & 1) << 7) + row) * K)
          + (ts << 6) + cs * 8;
      gload_lds16(gp, base + ((wave * 64 + j * 512) << 4));
    }
  };
  auto dsA = [&](int cb, int mi, int kk) {
    const int r = wm + mi * 16 + l15;
    const int cs = (kk * 4 + q) ^ (r & 7);
    return *(const bf16x8*)(ldsc + (cb << 16) + r * 128 + cs * 16);
  };
  auto dsB = [&](int cb, int nj, int kk) {
    const int r = wn + nj * 16 + l15;
    const int cs = (kk * 4 + q) ^ (r & 7);
    return *(const bf16x8*)(ldsc + (cb << 16) + 32768 + r * 128 + cs * 16);
  };

  stage(0, 0); stage(0, 1); stage(0, 2); stage(0, 3);
  stage(1, 0);
  asm volatile("s_waitcnt vmcnt(2)" ::: "memory");
  __builtin_amdgcn_s_barrier();

  bf16x8 aF[4][2], bF[4][2];
#pragma unroll 1
  for (int t = 0; t < nt; ++t) {
    const int cb = t & 1;
#pragma unroll
    for (int mi = 0; mi < 4; ++mi)
#pragma unroll
      for (int kk = 0; kk < 2; ++kk) aF[mi][kk] = dsA(cb, mi, kk);
#pragma unroll
    for (int nj = 0; nj < 2; ++nj)
#pragma unroll
      for (int kk = 0; kk < 2; ++kk) bF[nj][kk] = dsB(cb, nj, kk);
    stage(t + 1, 1);
    GEMM8P_SYNC_PRE();
    GEMM8P_QUAD(0, 0);
    GEMM8P_SYNC_POST();
#pragma unroll
    for (int nj = 2; nj < 4; ++nj)
#pragma unroll
      for (int kk = 0; kk < 2; ++kk) bF[nj][kk] = dsB(cb, nj, kk);
    stage(t + 1, 2);
    GEMM8P_SYNC_PRE();
    GEMM8P_QUAD(0, 2);
    GEMM8P_SYNC_POST();
#pragma unroll
    for (int mi = 0; mi < 4; ++mi)
#pragma unroll
      for (int kk = 0; kk < 2; ++kk) aF[mi][kk] = dsA(cb, 4 + mi, kk);
    stage(t + 1, 3);
    GEMM8P_SYNC_PRE();
    GEMM8P_QUAD(4, 2);
    GEMM8P_SYNC_POST();
    stage(t + 2, 0);
    if (t + 2 < nt) { asm volatile("s_waitcnt vmcnt(2)" ::: "memory"); }
    else            { asm volatile("s_waitcnt vmcnt(0)" ::: "memory"); }
    __builtin_amdgcn_s_barrier();
    __builtin_amdgcn_s_setprio(1);
    GEMM8P_QUAD(4, 0);
    GEMM8P_SYNC_POST();
  }

  // ---- coalesced epilogue via LDS bounce (slab 32 x 264 ushort) ----------
  ushort* slab = (ushort*)ldsc;
  float bv[4];
#pragma unroll
  for (int nj = 0; nj < 4; ++nj) bv[nj] = bias[blockN + wn + nj * 16 + l15];
  const int srow = (wave >> 2) * 16 + q * 4;        // + r
  const int scol = wn + l15;                        // + nj*16
  const int rs = tid >> 4;                          // slab row to read
  const int rc = (tid & 15) * 16;                   // slab col to read
  const long orow0 = blockM + (rs >> 4) * 128 + (rs & 15);
#pragma unroll 1
  for (int mi = 0; mi < 8; ++mi) {
    __syncthreads();   // slab free (K-loop done / prev mi reads done)
#pragma unroll
    for (int nj = 0; nj < 4; ++nj)
#pragma unroll
      for (int r = 0; r < 4; ++r) {
        float v = fmaxf(acc[mi][nj][r] + bv[nj], 0.0f);
        slab[(srow + r) * 264 + scol + nj * 16] = f2bf(v);
      }
    __syncthreads();
    bf16x8 v0 = *(const bf16x8*)(slab + rs * 264 + rc);
    bf16x8 v1 = *(const bf16x8*)(slab + rs * 264 + rc + 8);
    ushort* op = Cout + (orow0 + mi * 16) * ldc + blockN + rc;
    *(bf16x8*)op = v0;
    *(bf16x8*)(op + 8) = v1;
  }
}

// ---------------------------------------------------------------------------
// Skinny final layer: C[M,24] f32 = A[M,1024]bf16 x W3T[32,1024]bf16^T + b3.
// Round-11: replaces gemm_bt<64,32,...> (32 K-steps x 2 barriers/step,
// latency-bound, est ~50-60 us). New: stage ALL of B (32x1024, rows 24-31
// pre-zeroed by transpose_body) into LDS once (row pad 1032 -> 2-way banks),
// then a BARRIER-FREE per-wave loop: 32 K-chunks of {1 global bf16x8 A-load,
// 2 LDS b128 B-reads, 2 MFMAs}. Fragment mapping + ascending-K accumulation
// identical to gemm_bt -> bit-identical numerics.
// ---------------------------------------------------------------------------
__global__ __launch_bounds__(256) void gemm_skinny(
    const ushort* __restrict__ A, const ushort* __restrict__ Bt,
    const float* __restrict__ bias, float* __restrict__ Cout, int nvalid) {
  __shared__ __align__(16) ushort Bl[32 * 1032];
  const int tid = threadIdx.x, wave = tid >> 6, lane = tid & 63;
  const int l15 = lane & 15, q = lane >> 4;

  // stage B: 16 passes; waves {0,1} row p*2+0 halves, {2,3} row p*2+1 halves
#pragma unroll
  for (int p = 0; p < 16; ++p) {
    const int r = p * 2 + (wave >> 1);
    const int half = wave & 1;
    gload_lds16(Bt + r * 1024 + half * 512 + lane * 8,
                (char*)Bl + (r * 1032 + half * 512) * 2);
  }
  __syncthreads();   // implies vmcnt(0) drain

  const long rowbase = (long)blockIdx.x * 64 + wave * 16;
  f32x4 acc0 = {0.0f, 0.0f, 0.0f, 0.0f};
  f32x4 acc1 = {0.0f, 0.0f, 0.0f, 0.0f};
  const ushort* ap = A + (rowbase + l15) * 1024 + q * 8;
  const ushort* b0p = Bl + l15 * 1032 + q * 8;
  const ushort* b1p = Bl + (16 + l15) * 1032 + q * 8;
#pragma unroll 4
  for (int kc = 0; kc < 32; ++kc) {
    bf16x8 af = *(const bf16x8*)(ap + kc * 32);
    bf16x8 b0 = *(const bf16x8*)(b0p + kc * 32);
    bf16x8 b1 = *(const bf16x8*)(b1p + kc * 32);
    acc0 = __builtin_amdgcn_mfma_f32_16x16x32_bf16(af, b0, acc0, 0, 0, 0);
    acc1 = __builtin_amdgcn_mfma_f32_16x16x32_bf16(af, b1, acc1, 0, 0, 0);
  }
  // D: row = rowbase + q*4 + r, col = t*16 + l15 (store cols < nvalid)
#pragma unroll
  for (int r = 0; r < 4; ++r) {
    const long row = rowbase + q * 4 + r;
    Cout[row * nvalid + l15] = acc0[r] + bias[l15];
    if (l15 < 8) Cout[row * nvalid + 16 + l15] = acc1[r] + bias[16 + l15];
  }
}

// ---------------------------------------------------------------------------
// ADMM via MFMA — round-0 kernel (best measured across 9 rewrite attempts).
// 16 batch rows per wave; C-layout state; intra-wave LDS f32 transpose
// (2-way-aliased, free per m136); 18 K32 MFMAs, T register-resident.
// ---------------------------------------------------------------------------
__global__ __launch_bounds__(256) void admm_mfma(
    const float* raw,
    const ushort* __restrict__ Th, const ushort* __restrict__ Tl,
    const ushort* __restrict__ T0h, const ushort* __restrict__ T0l,
    const float* __restrict__ blp, const float* __restrict__ bup,
    float* outp) {
  __shared__ __align__(16) float Ubuf[4][16][68];
  const int tid = threadIdx.x, wave = tid >> 6, lane = tid & 63;
  const int l15 = lane & 15, q = lane >> 4;
  const long rowbase = (long)blockIdx.x * 64 + wave * 16;
  float (*U)[68] = Ubuf[wave];

  // zero K-pad region (cols 48..63) once; never written again
  for (int idx = lane; idx < 256; idx += 64)
    U[idx >> 4][48 + (idx & 15)] = 0.0f;

  float bl[3], bu[3];
#pragma unroll
  for (int t = 0; t < 3; ++t) { bl[t] = blp[16 * t + l15]; bu[t] = bup[16 * t + l15]; }

  // ---- peel: base = W_1 = T0 * q ------------------------------------------
  f32x4 W[3], base[3];
  {
    bf16x8 t0h[3], t0l[3];
#pragma unroll
    for (int t = 0; t < 3; ++t) {
      t0h[t] = *(const bf16x8*)(T0h + (16 * t + l15) * 32 + q * 8);
      t0l[t] = *(const bf16x8*)(T0l + (16 * t + l15) * 32 + q * 8);
    }
    float qa[8];
    if (q < 3) {
      const float* rp = raw + (rowbase + l15) * 24 + q * 8;
      float4 v0 = *(const float4*)rp;
      float4 v1 = *(const float4*)(rp + 4);
      qa[0] = v0.x; qa[1] = v0.y; qa[2] = v0.z; qa[3] = v0.w;
      qa[4] = v1.x; qa[5] = v1.y; qa[6] = v1.z; qa[7] = v1.w;
    } else {
#pragma unroll
      for (int j = 0; j < 8; ++j) qa[j] = 0.0f;
    }
    bf16x8 qhi, qlo;
    splitPack(qa, qhi, qlo);
#pragma unroll
    for (int t = 0; t < 3; ++t) {
      f32x4 acc = {0.0f, 0.0f, 0.0f, 0.0f};
      acc = __builtin_amdgcn_mfma_f32_16x16x32_bf16(qhi, t0h[t], acc, 0, 0, 0);
      acc = __builtin_amdgcn_mfma_f32_16x16x32_bf16(qlo, t0h[t], acc, 0, 0, 0);
      acc = __builtin_amdgcn_mfma_f32_16x16x32_bf16(qhi, t0l[t], acc, 0, 0, 0);
      base[t] = acc; W[t] = acc;
    }
  }

  // ---- T B-fragments (register-resident, shared layout) -------------------
  bf16x8 tbh[2][3], tbl[2][3];
#pragma unroll
  for (int c = 0; c < 2; ++c)
#pragma unroll
    for (int t = 0; t < 3; ++t) {
      tbh[c][t] = *(const bf16x8*)(Th + (16 * t + l15) * 64 + 32 * c + q * 8);
      tbl[c][t] = *(const bf16x8*)(Tl + (16 * t + l15) * 64 + 32 * c + q * 8);
    }

  float yb0[4], yb1[4];
#pragma unroll 1
  for (int it = 1; it < ADMM_ITERS; ++it) {
    f32x4 C[3];
#pragma unroll
    for (int t = 0; t < 3; ++t) {
#pragma unroll
      for (int r = 0; r < 4; ++r) {
        float w = W[t][r];
        float z = fminf(fmaxf(w, bl[t]), bu[t]);
        float u = 2.0f * z - w;
        float y = w - z;
        C[t][r] = base[t][r] + y;
        if (t == 0) yb0[r] = y;
        if (t == 1) yb1[r] = y;
        U[q * 4 + r][16 * t + l15] = u;
      }
    }
    bf16x8 uh[2], ul[2];
#pragma unroll
    for (int c = 0; c < 2; ++c) {
      const float* up = &U[l15][32 * c + q * 8];
      float4 a0 = *(const float4*)up;
      float4 a1 = *(const float4*)(up + 4);
      float ua[8] = {a0.x, a0.y, a0.z, a0.w, a1.x, a1.y, a1.z, a1.w};
      splitPack(ua, uh[c], ul[c]);
    }
#pragma unroll
    for (int t = 0; t < 3; ++t) {
      f32x4 acc = C[t];
#pragma unroll
      for (int c = 0; c < 2; ++c) {
        acc = __builtin_amdgcn_mfma_f32_16x16x32_bf16(uh[c], tbh[c][t], acc, 0, 0, 0);
        acc = __builtin_amdgcn_mfma_f32_16x16x32_bf16(ul[c], tbh[c][t], acc, 0, 0, 0);
        acc = __builtin_amdgcn_mfma_f32_16x16x32_bf16(uh[c], tbl[c][t], acc, 0, 0, 0);
      }
      W[t] = acc;
    }
  }

  // X_100 = W_100,b - (W_99 - Z_99)_b ; store cols 0..23
#pragma unroll
  for (int r = 0; r < 4; ++r) {
    const long row = rowbase + q * 4 + r;
    outp[row * 24 + l15] = W[0][r] - yb0[r];
    if (l15 < 8) outp[row * 24 + 16 + l15] = W[1][r] - yb1[r];
  }
}

// ---------------------------------------------------------------------------
extern "C" void kernel_launch(void* const* d_in, const int* in_sizes, int n_in,
                              void* d_out, int out_size, void* d_ws, size_t ws_size,
                              hipStream_t stream) {
  const float* state = (const float*)d_in[0];
  const float* Aeq   = (const float*)d_in[1];
  const float* beq   = (const float*)d_in[2];
  const float* Ain   = (const float*)d_in[3];
  const float* bin   = (const float*)d_in[4];
  const float* ub    = (const float*)d_in[5];
  const float* lb    = (const float*)d_in[6];
  const float* W1    = (const float*)d_in[7];
  const float* b1    = (const float*)d_in[8];
  const float* W2    = (const float*)d_in[9];
  const float* b2    = (const float*)d_in[10];
  const float* W3    = (const float*)d_in[11];
  const float* b3    = (const float*)d_in[12];

  const int Bn = in_sizes[0] / 512;            // 16384
  char* ws = (char*)d_ws;
  ushort* stateB = (ushort*)(ws + 0);          // 16384x512 bf16  (16 MB)
  ushort* W1T    = (ushort*)(ws + 16777216);   // 1024x512        (1 MB)
  ushort* W2T    = (ushort*)(ws + 17825792);   // 1024x1024       (2 MB)
  ushort* W3T    = (ushort*)(ws + 19922944);   // 32x1024 (rows>=24 zero)
  ushort* Th     = (ushort*)(ws + 19993600);   // 48x64 bf16 hi
  ushort* Tl     = (ushort*)(ws + 19999744);   // 48x64 bf16 lo
  ushort* T0h    = (ushort*)(ws + 20005888);   // 48x32 bf16 hi
  ushort* T0l    = (ushort*)(ws + 20008960);   // 48x32 bf16 lo
  float*  blp    = (float*) (ws + 20012032);   // 48
  float*  bup    = (float*) (ws + 20012224);   // 48
  ushort* H1     = (ushort*)(ws + 21565440);   // 16384x1024 bf16 (32 MB)
  ushort* H2     = (ushort*)(ws + 55119872);   // 16384x1024 bf16 (32 MB)
  float*  rawb   = (float*)d_out;              // gemm3 out = admm in (in-place)

  const int n4 = (Bn * 512) / 4;
  const int nConv = n4 / 256;                  // 8192
  const int nPrep = nConv + 512 + 1024 + 32 + 1;
  prep_all<<<nPrep, 256, 0, stream>>>(state, stateB, n4, W1, W1T, W2, W2T, W3, W3T,
                                      Aeq, beq, Ain, bin, ub, lb,
                                      Th, Tl, T0h, T0l, blp, bup);

  const int nblkN = 1024 / 256;                // 4
  const int nwg = (Bn / 256) * nblkN;          // 256 (div by 8 -> swizzle ok)
  gemm8p<<<nwg, 512, 0, stream>>>(stateB, W1T, b1, H1, 512, 1024, nblkN);
  gemm8p<<<nwg, 512, 0, stream>>>(H1, W2T, b2, H2, 1024, 1024, nblkN);
  gemm_skinny<<<Bn / 64, 256, 0, stream>>>(H2, W3T, b3, rawb, 24);

  admm_mfma<<<Bn / 64, 256, 0, stream>>>(rawb, Th, Tl, T0h, T0l, blp, bup,
                                         (float*)d_out);
}

// Round 12
// 237.036 us; speedup vs baseline: 1.2274x; 1.2274x over previous
//
#include <hip/hip_runtime.h>

using uint = unsigned int;
using ushort = unsigned short;

typedef __attribute__((ext_vector_type(8))) short bf16x8;
typedef __attribute__((ext_vector_type(4))) short bf16x4;
typedef __attribute__((ext_vector_type(4))) float f32x4;

#define ADMM_ITERS 100
#define RHO_C 1.0f
#define SIGMA_C 1e-6f

__device__ inline ushort f2bf(float f) {
  union { float f; uint u; } c; c.f = f;
  uint u = c.u;
  uint r = (u + 0x7fffu + ((u >> 16) & 1u)) >> 16;
  return (ushort)r;
}

__device__ inline void gload_lds16(const void* g, void* l) {
  __builtin_amdgcn_global_load_lds(
      (const __attribute__((address_space(1))) void*)g,
      (__attribute__((address_space(3))) void*)l, 16, 0, 0);
}

// Split 8 f32 -> hi/lo bf16x8 by TRUNCATION (hi = mantissa-masked; lo = exact
// residual, truncated). Residual error ~2^-16 relative.
__device__ inline void splitPack(const float* x, bf16x8& hi, bf16x8& lo) {
#pragma unroll
  for (int j = 0; j < 8; ++j) {
    uint b = __float_as_uint(x[j]);
    uint hb = b & 0xffff0000u;
    float lf = x[j] - __uint_as_float(hb);
    hi[j] = (short)(b >> 16);
    lo[j] = (short)(__float_as_uint(lf) >> 16);
  }
}

// ---------------------------------------------------------------------------
// prep bodies (fused into prep_all)
// ---------------------------------------------------------------------------
__device__ void transpose_body(const float* __restrict__ in, ushort* __restrict__ out,
                               int R, int C, int Cout, int bx, int by, int tid) {
  __shared__ float t[32][33];
  const int c0 = bx * 32, r0 = by * 32;
  const int tx = tid & 31, ty = tid >> 5;
  for (int rr = ty; rr < 32; rr += 8) {
    int r = r0 + rr, c = c0 + tx;
    float v = 0.0f;
    if (r < R && c < C) v = in[(long)r * C + c];
    t[rr][tx] = v;
  }
  __syncthreads();
  for (int rr = ty; rr < 32; rr += 8) {
    int c = c0 + rr, r = r0 + tx;
    if (c < Cout && r < R) out[(long)c * R + r] = f2bf(t[tx][rr]);
  }
}

// ADMM setup -> MFMA operand form (round-0 layout, no permutation).
// W-state iteration (verified): u = 2*clip(W)-W,
//   W' = base + T*u + (W - Z),  T = [[2Minv, G],[2*A12*Minv, A12*G]] (36x36)
//   base = T0*q per row,       T0 = [[Minv],[A12*Minv]] (36x24)
// Outputs row-major [n_out][k_in], bf16 hi+lo (rounded split):
// Th/Tl [48][64], T0h/T0l [48][32], bounds bl/bu [48].
__device__ void setup_body(const float* __restrict__ Aeq, const float* __restrict__ beq,
                           const float* __restrict__ A, const float* __restrict__ b,
                           const float* __restrict__ ub, const float* __restrict__ lb,
                           ushort* __restrict__ Th, ushort* __restrict__ Tl,
                           ushort* __restrict__ T0h, ushort* __restrict__ T0l,
                           float* __restrict__ blp, float* __restrict__ bup, int t) {
  __shared__ float Aug[24][48];
  __shared__ float A12[12 * 24];
  __shared__ float fac[24];
  __shared__ float Tx[24][36];
  for (int i = t; i < 48 * 64; i += 256) { Th[i] = 0; Tl[i] = 0; }
  for (int i = t; i < 48 * 32; i += 256) { T0h[i] = 0; T0l[i] = 0; }
  if (t < 96)  A12[t] = Aeq[t];
  if (t < 192) A12[96 + t] = A[t];
  __syncthreads();
  for (int idx = t; idx < 576; idx += 256) {
    int j = idx / 24, k = idx % 24;
    float s = (j == k) ? (1.0f + SIGMA_C + 2.0f * RHO_C) : 0.0f;
    for (int r = 0; r < 12; ++r) s += RHO_C * A12[r * 24 + j] * A12[r * 24 + k];
    Aug[j][k] = s;
    Aug[j][24 + k] = (j == k) ? 1.0f : 0.0f;
  }
  __syncthreads();
  for (int p = 0; p < 24; ++p) {
    float rp = 1.0f / Aug[p][p];
    if (t < 24) fac[t] = Aug[t][p];
    __syncthreads();
    if (t < 48) Aug[p][t] *= rp;
    __syncthreads();
    for (int idx = t; idx < 24 * 48; idx += 256) {
      int r = idx / 48, c = idx % 48;
      if (r != p) Aug[r][c] -= fac[r] * Aug[p][c];
    }
    __syncthreads();
  }
  auto splitStore = [](ushort* hp, ushort* lp, int i, float v) {
    ushort hs = f2bf(v);
    float hf = __uint_as_float(((uint)hs) << 16);
    ushort ls = f2bf(v - hf);
    hp[i] = hs; lp[i] = ls;
  };
  for (int idx = t; idx < 24 * 36; idx += 256) {
    int n = idx / 36, k = idx % 36;
    float v;
    if (k < 24) v = 2.0f * Aug[n][24 + k];
    else {
      v = 0.0f;
      for (int j = 0; j < 24; ++j) v += Aug[n][24 + j] * A12[(k - 24) * 24 + j];
    }
    Tx[n][k] = v;
    splitStore(Th, Tl, n * 64 + k, v);
  }
  __syncthreads();
  for (int idx = t; idx < 12 * 36; idx += 256) {
    int m = idx / 36, k = idx % 36;
    float v = 0.0f;
    for (int j = 0; j < 24; ++j) v += A12[m * 24 + j] * Tx[j][k];
    splitStore(Th, Tl, (24 + m) * 64 + k, v);
  }
  for (int idx = t; idx < 36 * 24; idx += 256) {
    int n = idx / 24, k = idx % 24;
    float v;
    if (n < 24) v = Aug[n][24 + k];
    else {
      v = 0.0f;
      for (int j = 0; j < 24; ++j) v += A12[(n - 24) * 24 + j] * Aug[j][24 + k];
    }
    splitStore(T0h, T0l, n * 32 + k, v);
  }
  if (t < 48) {
    float lv, uv;
    if (t < 24)      { lv = lb[t]; uv = ub[t]; }
    else if (t < 28) { lv = beq[t - 24]; uv = lv; }
    else if (t < 36) { lv = -1e30f; uv = b[t - 28]; }
    else             { lv = -1e30f; uv = 1e30f; }
    blp[t] = lv; bup[t] = uv;
  }
}

// Fused prep: [0,nConv) convert | [+512) W1T | [+1024) W2T | [+32) W3T | [1) setup
__global__ void prep_all(
    const float* __restrict__ state, ushort* __restrict__ stateB, int n4,
    const float* __restrict__ W1, ushort* __restrict__ W1T,
    const float* __restrict__ W2, ushort* __restrict__ W2T,
    const float* __restrict__ W3, ushort* __restrict__ W3T,
    const float* __restrict__ Aeq, const float* __restrict__ beq,
    const float* __restrict__ A, const float* __restrict__ b,
    const float* __restrict__ ub, const float* __restrict__ lb,
    ushort* __restrict__ Th, ushort* __restrict__ Tl,
    ushort* __restrict__ T0h, ushort* __restrict__ T0l,
    float* __restrict__ blp, float* __restrict__ bup) {
  const int nConv = n4 >> 8;
  int bb = blockIdx.x;
  if (bb < nConv) {
    int i = bb * 256 + threadIdx.x;
    if (i < n4) {
      float4 v = ((const float4*)state)[i];
      uint2 p;
      p.x = (uint)f2bf(v.x) | ((uint)f2bf(v.y) << 16);
      p.y = (uint)f2bf(v.z) | ((uint)f2bf(v.w) << 16);
      ((uint2*)stateB)[i] = p;
    }
    return;
  }
  bb -= nConv;
  if (bb < 512)  { transpose_body(W1, W1T, 512, 1024, 1024, bb & 31, bb >> 5, threadIdx.x); return; }
  bb -= 512;
  if (bb < 1024) { transpose_body(W2, W2T, 1024, 1024, 1024, bb & 31, bb >> 5, threadIdx.x); return; }
  bb -= 1024;
  if (bb < 32)   { transpose_body(W3, W3T, 1024, 24, 32, 0, bb, threadIdx.x); return; }
  setup_body(Aeq, beq, A, b, ub, lb, Th, Tl, T0h, T0l, blp, bup, threadIdx.x);
}

// ---------------------------------------------------------------------------
// 256x256 8-phase bf16 GEMM (T1+T2+T3+T4+T5).
// Round-12: epilogue mi-loop FULLY unrolled — r11's `#pragma unroll 1` made
// acc[mi] runtime-indexed -> whole accumulator spilled to scratch (VGPR 112,
// WRITE_SIZE 5x, +15 us/dispatch; rule #20). Static indexing keeps acc in
// registers; LDS-bounce + 16B coalesced stores retained.
// ---------------------------------------------------------------------------
#define GEMM8P_QUAD(MI0, NJ0)                                                 \
  _Pragma("unroll") for (int mi_ = 0; mi_ < 4; ++mi_)                         \
  _Pragma("unroll") for (int nj_ = 0; nj_ < 2; ++nj_)                         \
  _Pragma("unroll") for (int kk_ = 0; kk_ < 2; ++kk_)                         \
    acc[(MI0) + mi_][(NJ0) + nj_] = __builtin_amdgcn_mfma_f32_16x16x32_bf16(  \
        aF[mi_][kk_], bF[(NJ0) + nj_][kk_], acc[(MI0) + mi_][(NJ0) + nj_],    \
        0, 0, 0);

#define GEMM8P_SYNC_PRE()                              \
  __builtin_amdgcn_s_barrier();                        \
  asm volatile("s_waitcnt lgkmcnt(0)" ::: "memory");   \
  __builtin_amdgcn_sched_barrier(0);                   \
  __builtin_amdgcn_s_setprio(1);

#define GEMM8P_SYNC_POST()                             \
  __builtin_amdgcn_s_setprio(0);                       \
  __builtin_amdgcn_s_barrier();

__global__ __launch_bounds__(512, 2) void gemm8p(
    const ushort* __restrict__ A, const ushort* __restrict__ Bt,
    const float* __restrict__ bias, ushort* __restrict__ Cout,
    int K, int ldc, int nblk_n) {
  __shared__ __align__(16) char ldsc[131072];   // [2 buf][A 32K | B 32K]

  const int nwg = gridDim.x;
  const int bid = blockIdx.x;
  const int swz = (bid & 7) * (nwg >> 3) + (bid >> 3);
  const int blockM = (swz / nblk_n) * 256;
  const int blockN = (swz % nblk_n) * 256;

  const int tid = threadIdx.x;
  const int wave = tid >> 6;
  const int lane = tid & 63;
  const int l15 = lane & 15;
  const int q = lane >> 4;
  const int wm = (wave >> 2) * 128;
  const int wn = (wave & 3) * 64;
  const int nt = K >> 6;

  f32x4 acc[8][4] = {};

  auto stage = [&](int ts, int h) {
    if (ts >= nt) return;
    char* base = ldsc + ((ts & 1) << 16) + (h << 14);
#pragma unroll
    for (int j = 0; j < 2; ++j) {
      const int idx = wave * 64 + j * 512 + lane;
      const int row = idx >> 3;
      const int cs = (idx & 7) ^ (row & 7);
      const ushort* gp =
          (h < 2 ? A + (long)(blockM + ((h & 1) << 7) + row) * K
                 : Bt + (long)(blockN + ((h & 1) << 7) + row) * K)
          + (ts << 6) + cs * 8;
      gload_lds16(gp, base + ((wave * 64 + j * 512) << 4));
    }
  };
  auto dsA = [&](int cb, int mi, int kk) {
    const int r = wm + mi * 16 + l15;
    const int cs = (kk * 4 + q) ^ (r & 7);
    return *(const bf16x8*)(ldsc + (cb << 16) + r * 128 + cs * 16);
  };
  auto dsB = [&](int cb, int nj, int kk) {
    const int r = wn + nj * 16 + l15;
    const int cs = (kk * 4 + q) ^ (r & 7);
    return *(const bf16x8*)(ldsc + (cb << 16) + 32768 + r * 128 + cs * 16);
  };

  stage(0, 0); stage(0, 1); stage(0, 2); stage(0, 3);
  stage(1, 0);
  asm volatile("s_waitcnt vmcnt(2)" ::: "memory");
  __builtin_amdgcn_s_barrier();

  bf16x8 aF[4][2], bF[4][2];
#pragma unroll 1
  for (int t = 0; t < nt; ++t) {
    const int cb = t & 1;
#pragma unroll
    for (int mi = 0; mi < 4; ++mi)
#pragma unroll
      for (int kk = 0; kk < 2; ++kk) aF[mi][kk] = dsA(cb, mi, kk);
#pragma unroll
    for (int nj = 0; nj < 2; ++nj)
#pragma unroll
      for (int kk = 0; kk < 2; ++kk) bF[nj][kk] = dsB(cb, nj, kk);
    stage(t + 1, 1);
    GEMM8P_SYNC_PRE();
    GEMM8P_QUAD(0, 0);
    GEMM8P_SYNC_POST();
#pragma unroll
    for (int nj = 2; nj < 4; ++nj)
#pragma unroll
      for (int kk = 0; kk < 2; ++kk) bF[nj][kk] = dsB(cb, nj, kk);
    stage(t + 1, 2);
    GEMM8P_SYNC_PRE();
    GEMM8P_QUAD(0, 2);
    GEMM8P_SYNC_POST();
#pragma unroll
    for (int mi = 0; mi < 4; ++mi)
#pragma unroll
      for (int kk = 0; kk < 2; ++kk) aF[mi][kk] = dsA(cb, 4 + mi, kk);
    stage(t + 1, 3);
    GEMM8P_SYNC_PRE();
    GEMM8P_QUAD(4, 2);
    GEMM8P_SYNC_POST();
    stage(t + 2, 0);
    if (t + 2 < nt) { asm volatile("s_waitcnt vmcnt(2)" ::: "memory"); }
    else            { asm volatile("s_waitcnt vmcnt(0)" ::: "memory"); }
    __builtin_amdgcn_s_barrier();
    __builtin_amdgcn_s_setprio(1);
    GEMM8P_QUAD(4, 0);
    GEMM8P_SYNC_POST();
  }

  // ---- coalesced epilogue via LDS bounce (slab 32 x 264 ushort) ----------
  // FULLY unrolled: acc stays register-resident (r11 spill fix).
  ushort* slab = (ushort*)ldsc;
  float bv[4];
#pragma unroll
  for (int nj = 0; nj < 4; ++nj) bv[nj] = bias[blockN + wn + nj * 16 + l15];
  const int srow = (wave >> 2) * 16 + q * 4;        // + r
  const int scol = wn + l15;                        // + nj*16
  const int rs = tid >> 4;                          // slab row to read
  const int rc = (tid & 15) * 16;                   // slab col to read
  const long orow0 = blockM + (rs >> 4) * 128 + (rs & 15);
#pragma unroll
  for (int mi = 0; mi < 8; ++mi) {
    __syncthreads();   // slab free (K-loop done / prev mi reads done)
#pragma unroll
    for (int nj = 0; nj < 4; ++nj)
#pragma unroll
      for (int r = 0; r < 4; ++r) {
        float v = fmaxf(acc[mi][nj][r] + bv[nj], 0.0f);
        slab[(srow + r) * 264 + scol + nj * 16] = f2bf(v);
      }
    __syncthreads();
    bf16x8 v0 = *(const bf16x8*)(slab + rs * 264 + rc);
    bf16x8 v1 = *(const bf16x8*)(slab + rs * 264 + rc + 8);
    ushort* op = Cout + (orow0 + mi * 16) * ldc + blockN + rc;
    *(bf16x8*)op = v0;
    *(bf16x8*)(op + 8) = v1;
  }
}

// ---------------------------------------------------------------------------
// ADMM via MFMA — round-0 structure (best measured), round-12: final-layer
// GEMM FUSED in. Each wave computes its own raw[16x24] = H2[16rows,1024] @
// W3T^T + b3 inline: 32 barrier-free K-chunks of {1 HBM A-load, 2 W3T loads
// (64 KB total, L2-resident broadcast), 2 MFMAs} — bit-identical math to the
// removed gemm_skinny (same K order, same chains, f32 bias). Result is in
// D-layout (row=q*4+r, col=l15); transpose to peel layout via the existing
// Ubuf (intra-wave, DS in-order, no barrier; writes 2 lanes/bank = free).
// Removes one dispatch + the rawb HBM round-trip.
// ---------------------------------------------------------------------------
__global__ __launch_bounds__(256) void admm_mfma(
    const ushort* __restrict__ H2, const ushort* __restrict__ W3T,
    const float* __restrict__ b3,
    const ushort* __restrict__ Th, const ushort* __restrict__ Tl,
    const ushort* __restrict__ T0h, const ushort* __restrict__ T0l,
    const float* __restrict__ blp, const float* __restrict__ bup,
    float* outp) {
  __shared__ __align__(16) float Ubuf[4][16][68];
  const int tid = threadIdx.x, wave = tid >> 6, lane = tid & 63;
  const int l15 = lane & 15, q = lane >> 4;
  const long rowbase = (long)blockIdx.x * 64 + wave * 16;
  float (*U)[68] = Ubuf[wave];

  // zero K-pad region (cols 48..63) once; never written again
  for (int idx = lane; idx < 256; idx += 64)
    U[idx >> 4][48 + (idx & 15)] = 0.0f;

  float bl[3], bu[3];
#pragma unroll
  for (int t = 0; t < 3; ++t) { bl[t] = blp[16 * t + l15]; bu[t] = bup[16 * t + l15]; }

  // ---- fused final layer: raw = H2 @ W3T^T + b3 (bit-identical to old) ----
  {
    f32x4 acc0 = {0.0f, 0.0f, 0.0f, 0.0f};
    f32x4 acc1 = {0.0f, 0.0f, 0.0f, 0.0f};
    const ushort* ap = H2 + (rowbase + l15) * 1024 + q * 8;
    const ushort* b0p = W3T + l15 * 1024 + q * 8;
    const ushort* b1p = W3T + (16 + l15) * 1024 + q * 8;
#pragma unroll 4
    for (int kc = 0; kc < 32; ++kc) {
      bf16x8 af = *(const bf16x8*)(ap + kc * 32);
      bf16x8 b0 = *(const bf16x8*)(b0p + kc * 32);
      bf16x8 b1 = *(const bf16x8*)(b1p + kc * 32);
      acc0 = __builtin_amdgcn_mfma_f32_16x16x32_bf16(af, b0, acc0, 0, 0, 0);
      acc1 = __builtin_amdgcn_mfma_f32_16x16x32_bf16(af, b1, acc1, 0, 0, 0);
    }
    // D-layout -> U[local_row][col] (cols 0..23); DS in-order per wave
#pragma unroll
    for (int r = 0; r < 4; ++r) {
      U[q * 4 + r][l15] = acc0[r] + b3[l15];
      if (l15 < 8) U[q * 4 + r][16 + l15] = acc1[r] + b3[16 + l15];
    }
  }

  // ---- peel: base = W_1 = T0 * q ------------------------------------------
  f32x4 W[3], base[3];
  {
    bf16x8 t0h[3], t0l[3];
#pragma unroll
    for (int t = 0; t < 3; ++t) {
      t0h[t] = *(const bf16x8*)(T0h + (16 * t + l15) * 32 + q * 8);
      t0l[t] = *(const bf16x8*)(T0l + (16 * t + l15) * 32 + q * 8);
    }
    float qa[8];
    if (q < 3) {
      const float* rp = &U[l15][q * 8];
      float4 v0 = *(const float4*)rp;
      float4 v1 = *(const float4*)(rp + 4);
      qa[0] = v0.x; qa[1] = v0.y; qa[2] = v0.z; qa[3] = v0.w;
      qa[4] = v1.x; qa[5] = v1.y; qa[6] = v1.z; qa[7] = v1.w;
    } else {
#pragma unroll
      for (int j = 0; j < 8; ++j) qa[j] = 0.0f;
    }
    bf16x8 qhi, qlo;
    splitPack(qa, qhi, qlo);
#pragma unroll
    for (int t = 0; t < 3; ++t) {
      f32x4 acc = {0.0f, 0.0f, 0.0f, 0.0f};
      acc = __builtin_amdgcn_mfma_f32_16x16x32_bf16(qhi, t0h[t], acc, 0, 0, 0);
      acc = __builtin_amdgcn_mfma_f32_16x16x32_bf16(qlo, t0h[t], acc, 0, 0, 0);
      acc = __builtin_amdgcn_mfma_f32_16x16x32_bf16(qhi, t0l[t], acc, 0, 0, 0);
      base[t] = acc; W[t] = acc;
    }
  }

  // ---- T B-fragments (register-resident, shared layout) -------------------
  bf16x8 tbh[2][3], tbl[2][3];
#pragma unroll
  for (int c = 0; c < 2; ++c)
#pragma unroll
    for (int t = 0; t < 3; ++t) {
      tbh[c][t] = *(const bf16x8*)(Th + (16 * t + l15) * 64 + 32 * c + q * 8);
      tbl[c][t] = *(const bf16x8*)(Tl + (16 * t + l15) * 64 + 32 * c + q * 8);
    }

  float yb0[4], yb1[4];
#pragma unroll 1
  for (int it = 1; it < ADMM_ITERS; ++it) {
    f32x4 C[3];
#pragma unroll
    for (int t = 0; t < 3; ++t) {
#pragma unroll
      for (int r = 0; r < 4; ++r) {
        float w = W[t][r];
        float z = fminf(fmaxf(w, bl[t]), bu[t]);
        float u = 2.0f * z - w;
        float y = w - z;
        C[t][r] = base[t][r] + y;
        if (t == 0) yb0[r] = y;
        if (t == 1) yb1[r] = y;
        U[q * 4 + r][16 * t + l15] = u;
      }
    }
    bf16x8 uh[2], ul[2];
#pragma unroll
    for (int c = 0; c < 2; ++c) {
      const float* up = &U[l15][32 * c + q * 8];
      float4 a0 = *(const float4*)up;
      float4 a1 = *(const float4*)(up + 4);
      float ua[8] = {a0.x, a0.y, a0.z, a0.w, a1.x, a1.y, a1.z, a1.w};
      splitPack(ua, uh[c], ul[c]);
    }
#pragma unroll
    for (int t = 0; t < 3; ++t) {
      f32x4 acc = C[t];
#pragma unroll
      for (int c = 0; c < 2; ++c) {
        acc = __builtin_amdgcn_mfma_f32_16x16x32_bf16(uh[c], tbh[c][t], acc, 0, 0, 0);
        acc = __builtin_amdgcn_mfma_f32_16x16x32_bf16(ul[c], tbh[c][t], acc, 0, 0, 0);
        acc = __builtin_amdgcn_mfma_f32_16x16x32_bf16(uh[c], tbl[c][t], acc, 0, 0, 0);
      }
      W[t] = acc;
    }
  }

  // X_100 = W_100,b - (W_99 - Z_99)_b ; store cols 0..23
#pragma unroll
  for (int r = 0; r < 4; ++r) {
    const long row = rowbase + q * 4 + r;
    outp[row * 24 + l15] = W[0][r] - yb0[r];
    if (l15 < 8) outp[row * 24 + 16 + l15] = W[1][r] - yb1[r];
  }
}

// ---------------------------------------------------------------------------
extern "C" void kernel_launch(void* const* d_in, const int* in_sizes, int n_in,
                              void* d_out, int out_size, void* d_ws, size_t ws_size,
                              hipStream_t stream) {
  const float* state = (const float*)d_in[0];
  const float* Aeq   = (const float*)d_in[1];
  const float* beq   = (const float*)d_in[2];
  const float* Ain   = (const float*)d_in[3];
  const float* bin   = (const float*)d_in[4];
  const float* ub    = (const float*)d_in[5];
  const float* lb    = (const float*)d_in[6];
  const float* W1    = (const float*)d_in[7];
  const float* b1    = (const float*)d_in[8];
  const float* W2    = (const float*)d_in[9];
  const float* b2    = (const float*)d_in[10];
  const float* W3    = (const float*)d_in[11];
  const float* b3    = (const float*)d_in[12];

  const int Bn = in_sizes[0] / 512;            // 16384
  char* ws = (char*)d_ws;
  ushort* stateB = (ushort*)(ws + 0);          // 16384x512 bf16  (16 MB)
  ushort* W1T    = (ushort*)(ws + 16777216);   // 1024x512        (1 MB)
  ushort* W2T    = (ushort*)(ws + 17825792);   // 1024x1024       (2 MB)
  ushort* W3T    = (ushort*)(ws + 19922944);   // 32x1024 (rows>=24 zero)
  ushort* Th     = (ushort*)(ws + 19993600);   // 48x64 bf16 hi
  ushort* Tl     = (ushort*)(ws + 19999744);   // 48x64 bf16 lo
  ushort* T0h    = (ushort*)(ws + 20005888);   // 48x32 bf16 hi
  ushort* T0l    = (ushort*)(ws + 20008960);   // 48x32 bf16 lo
  float*  blp    = (float*) (ws + 20012032);   // 48
  float*  bup    = (float*) (ws + 20012224);   // 48
  ushort* H1     = (ushort*)(ws + 21565440);   // 16384x1024 bf16 (32 MB)
  ushort* H2     = (ushort*)(ws + 55119872);   // 16384x1024 bf16 (32 MB)

  const int n4 = (Bn * 512) / 4;
  const int nConv = n4 / 256;                  // 8192
  const int nPrep = nConv + 512 + 1024 + 32 + 1;
  prep_all<<<nPrep, 256, 0, stream>>>(state, stateB, n4, W1, W1T, W2, W2T, W3, W3T,
                                      Aeq, beq, Ain, bin, ub, lb,
                                      Th, Tl, T0h, T0l, blp, bup);

  const int nblkN = 1024 / 256;                // 4
  const int nwg = (Bn / 256) * nblkN;          // 256 (div by 8 -> swizzle ok)
  gemm8p<<<nwg, 512, 0, stream>>>(stateB, W1T, b1, H1, 512, 1024, nblkN);
  gemm8p<<<nwg, 512, 0, stream>>>(H1, W2T, b2, H2, 1024, 1024, nblkN);

  // final layer fused into admm (gemm_skinny removed)
  admm_mfma<<<Bn / 64, 256, 0, stream>>>(H2, W3T, b3, Th, Tl, T0h, T0l,
                                         blp, bup, (float*)d_out);
}